// Round 1
// baseline (222.669 us; speedup 1.0000x reference)
//
#include <hip/hip_runtime.h>
#include <math.h>

// ---------------------------------------------------------------------------
// LorentzSelfAttention — MI355X
//
// Key simplification (verified analytically): log_map here uses u = y + a*p,
// which has <u,u>_L = -1-3a^2 < 0 for on-hyperboloid points -> clamped to
// TINY always. So logv = C*(V_j + a_ij*Q_i)*dist_ij with C = 1/sqrt(1e-15).
// Similarly exp_map's vn^2 clamps (cosh=1, sinh/vn=1) and the final origin
// log-map clamps. Hence:
//   u_agg_i = C*(W_i + S_i*Q_i),  W_i = sum_j attn*dist*V_j,
//                                 S_i = sum_j attn*dist*alpha_ij
//   Y_i = mink_normalize(Q_i + u_agg_i), |time|
//   Ztan_i = dist0*C * (2*Y0, Ys),  dist0 = acosh(max(Y0,1+eps))
// ---------------------------------------------------------------------------

namespace {

constexpr int Bq   = 2;
constexpr int Tq   = 512;
constexpr int DMq  = 512;
constexpr int Hq   = 8;
constexpr int Aq   = 33;          // Lorentz ambient dim
constexpr int QKVN = 768;         // 3 * H * N_SP
constexpr int HAq  = 264;         // H * A

#define EPSF  1e-6f
#define CINV  3.16227766e7f       // 1/sqrt(1e-15)

// ---------------- Kernel 1: z = x @ [Wq;Wk;Wv]^T + b  (1024 x 768) ---------
__global__ __launch_bounds__(256) void gemm_qkv_kernel(
    const float* __restrict__ x,
    const float* __restrict__ Wq, const float* __restrict__ bq,
    const float* __restrict__ Wk, const float* __restrict__ bk,
    const float* __restrict__ Wv, const float* __restrict__ bv,
    float* __restrict__ z)
{
    __shared__ float As[64][17];
    __shared__ float Bs[64][17];
    const int n0 = blockIdx.x * 64;
    const int m0 = blockIdx.y * 64;
    const int t  = threadIdx.x;
    const int tx = t & 15, ty = t >> 4;
    const int lr = t >> 2;            // 0..63
    const int lc = (t & 3) * 4;       // 0,4,8,12

    float acc[4][4];
    #pragma unroll
    for (int r = 0; r < 4; ++r)
        #pragma unroll
        for (int c = 0; c < 4; ++c) acc[r][c] = 0.f;

    const int og = n0 + lr;
    const float* Wsel = (og < 256) ? Wq : (og < 512 ? Wk : Wv);
    const int orow = og & 255;

    for (int k0 = 0; k0 < DMq; k0 += 16) {
        const float4 av = *reinterpret_cast<const float4*>(&x[(m0 + lr) * DMq + k0 + lc]);
        As[lr][lc+0] = av.x; As[lr][lc+1] = av.y; As[lr][lc+2] = av.z; As[lr][lc+3] = av.w;
        const float4 bw = *reinterpret_cast<const float4*>(&Wsel[orow * DMq + k0 + lc]);
        Bs[lr][lc+0] = bw.x; Bs[lr][lc+1] = bw.y; Bs[lr][lc+2] = bw.z; Bs[lr][lc+3] = bw.w;
        __syncthreads();
        #pragma unroll
        for (int kk = 0; kk < 16; ++kk) {
            float a[4], b[4];
            #pragma unroll
            for (int r = 0; r < 4; ++r) a[r] = As[ty*4+r][kk];
            #pragma unroll
            for (int c = 0; c < 4; ++c) b[c] = Bs[tx*4+c][kk];
            #pragma unroll
            for (int r = 0; r < 4; ++r)
                #pragma unroll
                for (int c = 0; c < 4; ++c) acc[r][c] = fmaf(a[r], b[c], acc[r][c]);
        }
        __syncthreads();
    }
    #pragma unroll
    for (int c = 0; c < 4; ++c) {
        const int o = n0 + tx*4 + c;
        const float* bsel = (o < 256) ? bq : (o < 512 ? bk : bv);
        const float bias = bsel[o & 255];
        #pragma unroll
        for (int r = 0; r < 4; ++r)
            z[(m0 + ty*4 + r) * QKVN + o] = acc[r][c] + bias;
    }
}

// ---------------- Kernel 2: FL lift to hyperboloid -------------------------
// Q stored (b,h,T,A) row-contig; K,V stored (b,h,A,T) for coalesced j-reads.
__global__ __launch_bounds__(256) void fl_kernel(
    const float* __restrict__ z, float* __restrict__ Q,
    float* __restrict__ K, float* __restrict__ V)
{
    const int tid = blockIdx.x * 256 + threadIdx.x;   // < 24576
    const int bt = tid / 24;
    const int r  = tid - bt * 24;
    const int which = r >> 3;
    const int h     = r & 7;
    const float* zp = z + bt * QKVN + which * 256 + h * 32;

    float zv[32];
    float s2 = 0.f;
    #pragma unroll
    for (int k = 0; k < 32; ++k) { zv[k] = zp[k]; s2 = fmaf(zv[k], zv[k], s2); }
    const float rr = sqrtf(s2);
    const float rs = fminf(fmaxf(rr, 1e-12f), 18.0f);
    const float ch = coshf(rs), sh = sinhf(rs);
    const float sc = sh / rs;
    float y0 = ch;
    float ys[32];
    float mink = -y0 * y0;
    #pragma unroll
    for (int k = 0; k < 32; ++k) { ys[k] = sc * zv[k]; mink = fmaf(ys[k], ys[k], mink); }
    const float inv = rsqrtf(fmaxf(fabsf(mink), 1e-15f));
    y0 = fabsf(y0 * inv);

    const int b = bt >> 9, tt = bt & 511;
    const int bh = b * Hq + h;
    if (which == 0) {
        float* qp = Q + (bh * Tq + tt) * Aq;
        qp[0] = y0;
        #pragma unroll
        for (int k = 0; k < 32; ++k) qp[1 + k] = ys[k] * inv;
    } else {
        float* p = ((which == 1) ? K : V) + bh * Aq * Tq + tt;
        p[0] = y0;
        #pragma unroll
        for (int k = 0; k < 32; ++k) p[(1 + k) * Tq] = ys[k] * inv;
    }
}

// ---------------- Kernel 3: attention + Karcher step + origin log ----------
__global__ __launch_bounds__(256) void attn_kernel(
    const float* __restrict__ Q, const float* __restrict__ K,
    const float* __restrict__ V, float* __restrict__ Ztan)
{
    __shared__ float sQ[16][34];
    __shared__ float sS[16][512];
    __shared__ float sM[16], sInv[16];
    __shared__ float sSp[16][4];
    __shared__ float sW[16][34];

    const int bh = blockIdx.y;
    const int i0 = blockIdx.x * 16;
    const int t  = threadIdx.x;
    const float* Qb = Q + (bh * Tq + i0) * Aq;
    const float* Kb = K + bh * Aq * Tq;
    const float* Vb = V + bh * Aq * Tq;

    for (int idx = t; idx < 16 * Aq; idx += 256)
        sQ[idx / Aq][idx % Aq] = Qb[idx];
    __syncthreads();

    // P1: scores = -acosh(max(ip,1+eps))^2
    #pragma unroll
    for (int jj = 0; jj < 2; ++jj) {
        const int j = jj * 256 + t;
        float kreg[33];
        #pragma unroll
        for (int a = 0; a < 33; ++a) kreg[a] = Kb[a * Tq + j];
        #pragma unroll
        for (int i = 0; i < 16; ++i) {
            float dotv = 0.f;
            #pragma unroll
            for (int a = 1; a < 33; ++a) dotv = fmaf(sQ[i][a], kreg[a], dotv);
            const float ip = sQ[i][0] * kreg[0] - dotv;
            const float d  = acoshf(fmaxf(ip, 1.0f + EPSF));
            sS[i][j] = -d * d;
        }
    }
    __syncthreads();

    // P2: softmax stats (wave w handles 4 rows)
    const int wv = t >> 6, lane = t & 63;
    #pragma unroll
    for (int ii = 0; ii < 4; ++ii) {
        const int i = wv * 4 + ii;
        float m = -1e30f;
        #pragma unroll
        for (int q = 0; q < 8; ++q) m = fmaxf(m, sS[i][lane + 64 * q]);
        #pragma unroll
        for (int off = 32; off > 0; off >>= 1) m = fmaxf(m, __shfl_xor(m, off, 64));
        float sum = 0.f;
        #pragma unroll
        for (int q = 0; q < 8; ++q) sum += expf(sS[i][lane + 64 * q] - m);
        #pragma unroll
        for (int off = 32; off > 0; off >>= 1) sum += __shfl_xor(sum, off, 64);
        if (lane == 0) { sM[i] = m; sInv[i] = 1.0f / sum; }
    }
    __syncthreads();

    // P3: w_ij = attn*dist(alpha); S_i partials; overwrite sS with w
    float Sp[16];
    #pragma unroll
    for (int i = 0; i < 16; ++i) Sp[i] = 0.f;
    #pragma unroll
    for (int jj = 0; jj < 2; ++jj) {
        const int j = jj * 256 + t;
        float vreg[33];
        #pragma unroll
        for (int a = 0; a < 33; ++a) vreg[a] = Vb[a * Tq + j];
        #pragma unroll
        for (int i = 0; i < 16; ++i) {
            float dotv = 0.f;
            #pragma unroll
            for (int a = 1; a < 33; ++a) dotv = fmaf(sQ[i][a], vreg[a], dotv);
            const float al = sQ[i][0] * vreg[0] - dotv;
            const float dd = acoshf(fmaxf(al, 1.0f + EPSF));
            const float aij = expf(sS[i][j] - sM[i]) * sInv[i];
            const float w = aij * dd;
            sS[i][j] = w;
            Sp[i] = fmaf(w, al, Sp[i]);
        }
    }
    #pragma unroll
    for (int i = 0; i < 16; ++i) {
        float v = Sp[i];
        #pragma unroll
        for (int off = 32; off > 0; off >>= 1) v += __shfl_xor(v, off, 64);
        if (lane == 0) sSp[i][wv] = v;
    }
    __syncthreads();

    // P4: W_i[a] = sum_j w_ij * V[a][j]
    for (int task = t; task < 16 * 33; task += 256) {
        const int i = task / 33, a = task - i * 33;
        const float* vp = Vb + a * Tq;
        float acc0 = 0.f, acc1 = 0.f;
        for (int j = 0; j < 512; j += 2) {
            acc0 = fmaf(sS[i][j],     vp[j],     acc0);
            acc1 = fmaf(sS[i][j + 1], vp[j + 1], acc1);
        }
        sW[i][a] = acc0 + acc1;
    }
    __syncthreads();

    // P5: exp_map (degenerate) + project + origin log-map (degenerate)
    if (t < 16) {
        const int i = t;
        const float S = sSp[i][0] + sSp[i][1] + sSp[i][2] + sSp[i][3];
        float y[33];
        float q0 = sQ[i][0];
        y[0] = q0 + CINV * (sW[i][0] + S * q0);
        float mink = -y[0] * y[0];
        #pragma unroll
        for (int a = 1; a < 33; ++a) {
            const float q = sQ[i][a];
            y[a] = q + CINV * (sW[i][a] + S * q);
            mink = fmaf(y[a], y[a], mink);
        }
        const float inv = rsqrtf(fmaxf(fabsf(mink), 1e-15f));
        const float Y0 = fabsf(y[0] * inv);
        const float dist0 = acoshf(fmaxf(Y0, 1.0f + EPSF));
        const float coef = dist0 * CINV;
        const int b = bh >> 3, h = bh & 7;
        float* zp = Ztan + ((b * Tq + (i0 + i)) * HAq) + h * Aq;
        zp[0] = coef * (2.0f * Y0);
        #pragma unroll
        for (int a = 1; a < 33; ++a) zp[a] = coef * (y[a] * inv);
    }
}

// ---------------- Kernel 4: Z = Ztan(1024x264) @ Wo^T + bo -----------------
__global__ __launch_bounds__(256) void out_gemm_kernel(
    const float* __restrict__ Ztan, const float* __restrict__ Wo,
    const float* __restrict__ bo, float* __restrict__ out)
{
    __shared__ float As[64][9];
    __shared__ float Bs[64][9];
    const int n0 = blockIdx.x * 64;
    const int m0 = blockIdx.y * 64;
    const int t  = threadIdx.x;
    const int tx = t & 15, ty = t >> 4;
    const int lr = t >> 2;
    const int lc = (t & 3) * 2;

    float acc[4][4];
    #pragma unroll
    for (int r = 0; r < 4; ++r)
        #pragma unroll
        for (int c = 0; c < 4; ++c) acc[r][c] = 0.f;

    for (int k0 = 0; k0 < HAq; k0 += 8) {
        const float2 av = *reinterpret_cast<const float2*>(&Ztan[(m0 + lr) * HAq + k0 + lc]);
        As[lr][lc] = av.x; As[lr][lc + 1] = av.y;
        const float2 bw = *reinterpret_cast<const float2*>(&Wo[(n0 + lr) * HAq + k0 + lc]);
        Bs[lr][lc] = bw.x; Bs[lr][lc + 1] = bw.y;
        __syncthreads();
        #pragma unroll
        for (int kk = 0; kk < 8; ++kk) {
            float a[4], b[4];
            #pragma unroll
            for (int r = 0; r < 4; ++r) a[r] = As[ty*4+r][kk];
            #pragma unroll
            for (int c = 0; c < 4; ++c) b[c] = Bs[tx*4+c][kk];
            #pragma unroll
            for (int r = 0; r < 4; ++r)
                #pragma unroll
                for (int c = 0; c < 4; ++c) acc[r][c] = fmaf(a[r], b[c], acc[r][c]);
        }
        __syncthreads();
    }
    #pragma unroll
    for (int c = 0; c < 4; ++c) {
        const int o = n0 + tx*4 + c;
        const float bias = bo[o];
        #pragma unroll
        for (int r = 0; r < 4; ++r)
            out[(m0 + ty*4 + r) * 512 + o] = acc[r][c] + bias;
    }
}

} // namespace

// ---------------------------------------------------------------------------
extern "C" void kernel_launch(void* const* d_in, const int* in_sizes, int n_in,
                              void* d_out, int out_size, void* d_ws, size_t ws_size,
                              hipStream_t stream)
{
    const float* x  = (const float*)d_in[0];
    const float* Wq = (const float*)d_in[1];
    const float* bq = (const float*)d_in[2];
    const float* Wk = (const float*)d_in[3];
    const float* bk = (const float*)d_in[4];
    const float* Wv = (const float*)d_in[5];
    const float* bv = (const float*)d_in[6];
    const float* Wo = (const float*)d_in[7];
    const float* bo = (const float*)d_in[8];
    float* out = (float*)d_out;

    float* ws   = (float*)d_ws;
    float* z    = ws;                   // 1024*768 = 786432
    float* Qb   = ws + 786432;          // 16*512*33 = 270336
    float* Kb   = Qb + 270336;
    float* Vb   = Kb + 270336;
    float* Ztan = Vb + 270336;          // 1024*264 = 270336

    gemm_qkv_kernel<<<dim3(12, 16), 256, 0, stream>>>(x, Wq, bq, Wk, bk, Wv, bv, z);
    fl_kernel<<<96, 256, 0, stream>>>(z, Qb, Kb, Vb);
    attn_kernel<<<dim3(32, 16), 256, 0, stream>>>(Qb, Kb, Vb, Ztan);
    out_gemm_kernel<<<dim3(8, 16), 256, 0, stream>>>(Ztan, Wo, bo, out);
}

// Round 2
// 116.643 us; speedup vs baseline: 1.9090x; 1.9090x over previous
//
#include <hip/hip_runtime.h>
#include <math.h>

// ---------------------------------------------------------------------------
// LorentzSelfAttention — MI355X
//
// Degenerate-clamp simplification (verified analytically, passed R0):
//   log_map's <u,u>_L = -1-3a^2 < 0 -> clamped to TINY always =>
//   u_agg_i = C*(W_i + S_i*Q_i),  W_i = sum_j attn*dist*V_j,
//                                 S_i = sum_j attn*dist*alpha_ij
//   Y_i = mink_normalize(Q_i + u_agg_i), |time|
//   Ztan_i = dist0*C * (2*Y0, Ys),  dist0 = acosh(max(Y0,1+eps))
// ---------------------------------------------------------------------------

namespace {

constexpr int Tq   = 512;
constexpr int DMq  = 512;
constexpr int Hq   = 8;
constexpr int Aq   = 33;          // Lorentz ambient dim
constexpr int QKVN = 768;         // 3 * H * N_SP
constexpr int HAq  = 264;         // H * A

#define EPSF  1e-6f
#define CINV  3.16227766e7f       // 1/sqrt(1e-15)

__device__ __forceinline__ float facosh(float x) {
    // caller guarantees x >= 1+1e-6; v_sqrt + v_log + fma
    return __logf(x + __builtin_amdgcn_sqrtf(fmaf(x, x, -1.0f)));
}

// ---------------- Kernel 1: z = x @ [Wq;Wk;Wv]^T + b  (1024 x 768) ---------
__global__ __launch_bounds__(256) void gemm_qkv_kernel(
    const float* __restrict__ x,
    const float* __restrict__ Wq, const float* __restrict__ bq,
    const float* __restrict__ Wk, const float* __restrict__ bk,
    const float* __restrict__ Wv, const float* __restrict__ bv,
    float* __restrict__ z)
{
    __shared__ float As[64][17];
    __shared__ float Bs[64][17];
    const int n0 = blockIdx.x * 64;
    const int m0 = blockIdx.y * 64;
    const int t  = threadIdx.x;
    const int tx = t & 15, ty = t >> 4;
    const int lr = t >> 2;            // 0..63
    const int lc = (t & 3) * 4;       // 0,4,8,12

    float acc[4][4];
    #pragma unroll
    for (int r = 0; r < 4; ++r)
        #pragma unroll
        for (int c = 0; c < 4; ++c) acc[r][c] = 0.f;

    const int og = n0 + lr;
    const float* Wsel = (og < 256) ? Wq : (og < 512 ? Wk : Wv);
    const int orow = og & 255;

    for (int k0 = 0; k0 < DMq; k0 += 16) {
        const float4 av = *reinterpret_cast<const float4*>(&x[(m0 + lr) * DMq + k0 + lc]);
        As[lr][lc+0] = av.x; As[lr][lc+1] = av.y; As[lr][lc+2] = av.z; As[lr][lc+3] = av.w;
        const float4 bw = *reinterpret_cast<const float4*>(&Wsel[orow * DMq + k0 + lc]);
        Bs[lr][lc+0] = bw.x; Bs[lr][lc+1] = bw.y; Bs[lr][lc+2] = bw.z; Bs[lr][lc+3] = bw.w;
        __syncthreads();
        #pragma unroll
        for (int kk = 0; kk < 16; ++kk) {
            float a[4], b[4];
            #pragma unroll
            for (int r = 0; r < 4; ++r) a[r] = As[ty*4+r][kk];
            #pragma unroll
            for (int c = 0; c < 4; ++c) b[c] = Bs[tx*4+c][kk];
            #pragma unroll
            for (int r = 0; r < 4; ++r)
                #pragma unroll
                for (int c = 0; c < 4; ++c) acc[r][c] = fmaf(a[r], b[c], acc[r][c]);
        }
        __syncthreads();
    }
    #pragma unroll
    for (int c = 0; c < 4; ++c) {
        const int o = n0 + tx*4 + c;
        const float* bsel = (o < 256) ? bq : (o < 512 ? bk : bv);
        const float bias = bsel[o & 255];
        #pragma unroll
        for (int r = 0; r < 4; ++r)
            z[(m0 + ty*4 + r) * QKVN + o] = acc[r][c] + bias;
    }
}

// ---------------- Kernel 2: FL lift to hyperboloid -------------------------
// Q stored (b,h,T,A) row-contig; K,V stored (b,h,A,T) for coalesced j-reads.
__global__ __launch_bounds__(256) void fl_kernel(
    const float* __restrict__ z, float* __restrict__ Q,
    float* __restrict__ K, float* __restrict__ V)
{
    const int tid = blockIdx.x * 256 + threadIdx.x;   // < 24576
    const int bt = tid / 24;
    const int r  = tid - bt * 24;
    const int which = r >> 3;
    const int h     = r & 7;
    const float* zp = z + bt * QKVN + which * 256 + h * 32;

    float zv[32];
    float s2 = 0.f;
    #pragma unroll
    for (int k = 0; k < 32; ++k) { zv[k] = zp[k]; s2 = fmaf(zv[k], zv[k], s2); }
    const float rr = __builtin_amdgcn_sqrtf(s2);
    const float rs = fminf(fmaxf(rr, 1e-12f), 18.0f);
    const float e  = __expf(rs);
    const float ei = __builtin_amdgcn_rcpf(e);
    const float ch = 0.5f * (e + ei);
    float sc = 0.5f * (e - ei) / rs;
    if (rs < 1e-3f) sc = fmaf(rs * rs, 1.0f / 6.0f, 1.0f);
    float y0 = ch;
    float ys[32];
    float mink = -y0 * y0;
    #pragma unroll
    for (int k = 0; k < 32; ++k) { ys[k] = sc * zv[k]; mink = fmaf(ys[k], ys[k], mink); }
    const float inv = __builtin_amdgcn_rsqf(fmaxf(fabsf(mink), 1e-15f));
    y0 = fabsf(y0 * inv);

    const int b = bt >> 9, tt = bt & 511;
    const int bh = b * Hq + h;
    if (which == 0) {
        float* qp = Q + (bh * Tq + tt) * Aq;
        qp[0] = y0;
        #pragma unroll
        for (int k = 0; k < 32; ++k) qp[1 + k] = ys[k] * inv;
    } else {
        float* p = ((which == 1) ? K : V) + bh * Aq * Tq + tt;
        p[0] = y0;
        #pragma unroll
        for (int k = 0; k < 32; ++k) p[(1 + k) * Tq] = ys[k] * inv;
    }
}

// ---------------- Kernel 3: attention + Karcher step + origin log ----------
// 512 threads, 16 rows/block. Thread j owns column j everywhere except P4,
// where the block regroups as 16 (row-block x a-chunk) groups x 32 j-lanes.
__global__ __launch_bounds__(512) void attn_kernel(
    const float* __restrict__ Q, const float* __restrict__ K,
    const float* __restrict__ V, float* __restrict__ Ztan)
{
    __shared__ float sQs[16][32];     // spatial Q (a=1..32)
    __shared__ float sQ0[16];         // time Q
    __shared__ float sS[16][512];     // scores, then w
    __shared__ float sM[16], sInv[16];
    __shared__ float sSp[16][8];      // per-wave S partials
    __shared__ float part[16][8][36]; // P4 partials
    __shared__ float sW[16][33];
    __shared__ float sSum[16];

    const int bh = blockIdx.y;
    const int i0 = blockIdx.x * 16;
    const int t  = threadIdx.x;       // 0..511
    const int lane = t & 63, wv = t >> 6;

    const float* Qb = Q + (bh * Tq + i0) * Aq;
    const float* Kb = K + bh * Aq * Tq;
    const float* Vb = V + bh * Aq * Tq;

    for (int idx = t; idx < 16 * Aq; idx += 512) {
        const int i = idx / 33, a = idx - i * 33;
        if (a == 0) sQ0[i] = Qb[idx];
        else        sQs[i][a - 1] = Qb[idx];
    }
    __syncthreads();

    // ---- P1: scores = -acosh(ip)^2, thread = column j -----------------
    {
        const int j = t;
        const float k0 = Kb[j];
        float ks[32];
        #pragma unroll
        for (int k = 0; k < 32; ++k) ks[k] = Kb[(k + 1) * Tq + j];
        #pragma unroll
        for (int i = 0; i < 16; ++i) {
            float d0 = 0.f, d1 = 0.f, d2 = 0.f, d3 = 0.f;
            #pragma unroll
            for (int c = 0; c < 8; ++c) {
                const float4 q4 = *reinterpret_cast<const float4*>(&sQs[i][c * 4]);
                d0 = fmaf(q4.x, ks[c * 4 + 0], d0);
                d1 = fmaf(q4.y, ks[c * 4 + 1], d1);
                d2 = fmaf(q4.z, ks[c * 4 + 2], d2);
                d3 = fmaf(q4.w, ks[c * 4 + 3], d3);
            }
            const float ip = sQ0[i] * k0 - ((d0 + d1) + (d2 + d3));
            const float d  = facosh(fmaxf(ip, 1.0f + EPSF));
            sS[i][j] = -d * d;
        }
    }
    __syncthreads();

    // ---- P2: softmax stats, wave wv handles rows 2wv, 2wv+1 -----------
    #pragma unroll
    for (int ii = 0; ii < 2; ++ii) {
        const int i = wv * 2 + ii;
        float m = -1e30f;
        #pragma unroll
        for (int q = 0; q < 8; ++q) m = fmaxf(m, sS[i][lane + 64 * q]);
        #pragma unroll
        for (int off = 32; off > 0; off >>= 1) m = fmaxf(m, __shfl_xor(m, off, 64));
        float sum = 0.f;
        #pragma unroll
        for (int q = 0; q < 8; ++q) sum += __expf(sS[i][lane + 64 * q] - m);
        #pragma unroll
        for (int off = 32; off > 0; off >>= 1) sum += __shfl_xor(sum, off, 64);
        if (lane == 0) { sM[i] = m; sInv[i] = __builtin_amdgcn_rcpf(sum); }
    }
    __syncthreads();

    // ---- P3: w_ij = attn*dist(alpha); S partials; overwrite sS with w -
    {
        const int j = t;
        const float v0 = Vb[j];
        float vs[32];
        #pragma unroll
        for (int k = 0; k < 32; ++k) vs[k] = Vb[(k + 1) * Tq + j];
        float sp[16];
        #pragma unroll
        for (int i = 0; i < 16; ++i) {
            float d0 = 0.f, d1 = 0.f, d2 = 0.f, d3 = 0.f;
            #pragma unroll
            for (int c = 0; c < 8; ++c) {
                const float4 q4 = *reinterpret_cast<const float4*>(&sQs[i][c * 4]);
                d0 = fmaf(q4.x, vs[c * 4 + 0], d0);
                d1 = fmaf(q4.y, vs[c * 4 + 1], d1);
                d2 = fmaf(q4.z, vs[c * 4 + 2], d2);
                d3 = fmaf(q4.w, vs[c * 4 + 3], d3);
            }
            const float al = fmaxf(sQ0[i] * v0 - ((d0 + d1) + (d2 + d3)), 1.0f + EPSF);
            const float dd = facosh(al);
            const float aij = __expf(sS[i][j] - sM[i]) * sInv[i];
            const float w = aij * dd;
            sS[i][j] = w;
            sp[i] = w * al;
        }
        #pragma unroll
        for (int i = 0; i < 16; ++i) {
            float v = sp[i];
            #pragma unroll
            for (int off = 32; off > 0; off >>= 1) v += __shfl_xor(v, off, 64);
            if (lane == 0) sSp[i][wv] = v;
        }
    }
    __syncthreads();

    // ---- P4: W[i][a] = sum_j w_ij * V[a][j] ---------------------------
    // 16 groups: g = ig*4 + ag; rows ig*4..ig*4+3, a-chunk ag*9..ag*9+8.
    {
        const int jl = t & 31, g = t >> 5;
        const int ig = g >> 2, ag = g & 3;
        const int abase = ag * 9;
        float acc[4][9];
        #pragma unroll
        for (int r = 0; r < 4; ++r)
            #pragma unroll
            for (int k = 0; k < 9; ++k) acc[r][k] = 0.f;

        #pragma unroll
        for (int q = 0; q < 16; ++q) {
            const int j = q * 32 + jl;
            const float w0 = sS[ig * 4 + 0][j];
            const float w1 = sS[ig * 4 + 1][j];
            const float w2 = sS[ig * 4 + 2][j];
            const float w3 = sS[ig * 4 + 3][j];
            #pragma unroll
            for (int k = 0; k < 9; ++k) {
                // a up to 35 for ag==3: reads past V rows land in Ztan region
                // (readable); the resulting acc entries are never consumed.
                const float v = Vb[(abase + k) * Tq + j];
                acc[0][k] = fmaf(w0, v, acc[0][k]);
                acc[1][k] = fmaf(w1, v, acc[1][k]);
                acc[2][k] = fmaf(w2, v, acc[2][k]);
                acc[3][k] = fmaf(w3, v, acc[3][k]);
            }
        }
        #pragma unroll
        for (int r = 0; r < 4; ++r)
            #pragma unroll
            for (int k = 0; k < 9; ++k) {
                float v = acc[r][k];
                v += __shfl_xor(v, 1, 64);
                v += __shfl_xor(v, 2, 64);
                acc[r][k] = v;
            }
        if ((jl & 3) == 0) {
            const int sub = jl >> 2;
            #pragma unroll
            for (int r = 0; r < 4; ++r)
                #pragma unroll
                for (int k = 0; k < 9; ++k)
                    part[g][sub][r * 9 + k] = acc[r][k];
        }
    }
    __syncthreads();

    // ---- stage 2: fold 8 partials per (i,a); reduce S -----------------
    for (int task = t; task < 16 * 33; task += 512) {
        const int i = task / 33, a = task - i * 33;
        const int ag2 = a / 9, k = a - ag2 * 9;
        const int g2 = (i >> 2) * 4 + ag2;
        const int idx = (i & 3) * 9 + k;
        float s = 0.f;
        #pragma unroll
        for (int sub = 0; sub < 8; ++sub) s += part[g2][sub][idx];
        sW[i][a] = s;
    }
    if (t < 16) {
        float s = 0.f;
        #pragma unroll
        for (int w = 0; w < 8; ++w) s += sSp[t][w];
        sSum[t] = s;
    }
    __syncthreads();

    // ---- P5: degenerate exp_map + project + origin log-map ------------
    if (t < 16) {
        const int i = t;
        const float S  = sSum[i];
        const float q0 = sQ0[i];
        const float y0 = fmaf(CINV, fmaf(S, q0, sW[i][0]), q0);
        float mink = -y0 * y0;
        float yv[32];
        #pragma unroll
        for (int a = 1; a < 33; ++a) {
            const float qa = sQs[i][a - 1];
            const float ya = fmaf(CINV, fmaf(S, qa, sW[i][a]), qa);
            yv[a - 1] = ya;
            mink = fmaf(ya, ya, mink);
        }
        const float inv = __builtin_amdgcn_rsqf(fmaxf(fabsf(mink), 1e-15f));
        const float Y0 = fabsf(y0 * inv);
        const float dist0 = facosh(fmaxf(Y0, 1.0f + EPSF));
        const float coef = dist0 * CINV;
        const int b = bh >> 3, h = bh & 7;
        float* zp = Ztan + ((b * Tq + (i0 + i)) * HAq) + h * Aq;
        zp[0] = coef * (2.0f * Y0);
        #pragma unroll
        for (int a = 1; a < 33; ++a) zp[a] = coef * (yv[a - 1] * inv);
    }
}

// ---------------- Kernel 4: Z = Ztan(1024x264) @ Wo^T + bo -----------------
__global__ __launch_bounds__(256) void out_gemm_kernel(
    const float* __restrict__ Ztan, const float* __restrict__ Wo,
    const float* __restrict__ bo, float* __restrict__ out)
{
    __shared__ float As[64][9];
    __shared__ float Bs[64][9];
    const int n0 = blockIdx.x * 64;
    const int m0 = blockIdx.y * 64;
    const int t  = threadIdx.x;
    const int tx = t & 15, ty = t >> 4;
    const int lr = t >> 2;
    const int lc = (t & 3) * 2;

    float acc[4][4];
    #pragma unroll
    for (int r = 0; r < 4; ++r)
        #pragma unroll
        for (int c = 0; c < 4; ++c) acc[r][c] = 0.f;

    for (int k0 = 0; k0 < HAq; k0 += 8) {
        const float2 av = *reinterpret_cast<const float2*>(&Ztan[(m0 + lr) * HAq + k0 + lc]);
        As[lr][lc] = av.x; As[lr][lc + 1] = av.y;
        const float2 bw = *reinterpret_cast<const float2*>(&Wo[(n0 + lr) * HAq + k0 + lc]);
        Bs[lr][lc] = bw.x; Bs[lr][lc + 1] = bw.y;
        __syncthreads();
        #pragma unroll
        for (int kk = 0; kk < 8; ++kk) {
            float a[4], b[4];
            #pragma unroll
            for (int r = 0; r < 4; ++r) a[r] = As[ty*4+r][kk];
            #pragma unroll
            for (int c = 0; c < 4; ++c) b[c] = Bs[tx*4+c][kk];
            #pragma unroll
            for (int r = 0; r < 4; ++r)
                #pragma unroll
                for (int c = 0; c < 4; ++c) acc[r][c] = fmaf(a[r], b[c], acc[r][c]);
        }
        __syncthreads();
    }
    #pragma unroll
    for (int c = 0; c < 4; ++c) {
        const int o = n0 + tx*4 + c;
        const float bias = bo[o];
        #pragma unroll
        for (int r = 0; r < 4; ++r)
            out[(m0 + ty*4 + r) * 512 + o] = acc[r][c] + bias;
    }
}

} // namespace

// ---------------------------------------------------------------------------
extern "C" void kernel_launch(void* const* d_in, const int* in_sizes, int n_in,
                              void* d_out, int out_size, void* d_ws, size_t ws_size,
                              hipStream_t stream)
{
    const float* x  = (const float*)d_in[0];
    const float* Wq = (const float*)d_in[1];
    const float* bq = (const float*)d_in[2];
    const float* Wk = (const float*)d_in[3];
    const float* bk = (const float*)d_in[4];
    const float* Wv = (const float*)d_in[5];
    const float* bv = (const float*)d_in[6];
    const float* Wo = (const float*)d_in[7];
    const float* bo = (const float*)d_in[8];
    float* out = (float*)d_out;

    float* ws   = (float*)d_ws;
    float* z    = ws;                   // 1024*768 = 786432
    float* Qb   = ws + 786432;          // 16*512*33 = 270336
    float* Kb   = Qb + 270336;
    float* Vb   = Kb + 270336;
    float* Ztan = Vb + 270336;          // 1024*264 = 270336

    gemm_qkv_kernel<<<dim3(12, 16), 256, 0, stream>>>(x, Wq, bq, Wk, bk, Wv, bv, z);
    fl_kernel<<<96, 256, 0, stream>>>(z, Qb, Kb, Vb);
    attn_kernel<<<dim3(32, 16), 512, 0, stream>>>(Qb, Kb, Vb, Ztan);
    out_gemm_kernel<<<dim3(8, 16), 256, 0, stream>>>(Ztan, Wo, bo, out);
}

// Round 3
// 88.224 us; speedup vs baseline: 2.5239x; 1.3221x over previous
//
#include <hip/hip_runtime.h>
#include <math.h>

// ---------------------------------------------------------------------------
// LorentzSelfAttention — MI355X
//
// Degenerate-clamp simplification (verified analytically, passed R1/R2):
//   log_map's <u,u>_L = -1-3a^2 < 0 -> clamped to TINY always =>
//   u_agg_i = C*(W_i + S_i*Q_i),  W_i = sum_j attn*dist*V_j,
//                                 S_i = sum_j attn*dist*alpha_ij
//   Y_i = mink_normalize(Q_i + u_agg_i), |time|
//   Ztan_i = dist0*C * (2*Y0, Ys),  dist0 = acosh(max(Y0,1+eps))
//
// R3 changes: FL fused into QKV-GEMM epilogue (z round-trip + fl kernel gone);
// k-major (transposed) LDS staging in both GEMMs (float4 reads, FMA-bound);
// attn reads Q via wave-uniform scalar loads (no LDS Q staging); part[] LDS
// aliases sS[] (LDS 56->34KB). Q stored padded: [32 spatial][time][3 pad].
// ---------------------------------------------------------------------------

namespace {

constexpr int Tq   = 512;
constexpr int Hq   = 8;
constexpr int QS   = 36;          // padded Q row stride

#define EPSF  1e-6f
#define CINV  3.16227766e7f       // 1/sqrt(1e-15)

__device__ __forceinline__ float facosh(float x) {
    // caller guarantees x >= 1+1e-6
    return __logf(x + __builtin_amdgcn_sqrtf(fmaf(x, x, -1.0f)));
}

// ---------------- Kernel 1: QKV GEMM + fused FL lift -----------------------
// z-tile (64 rows x 64 cols) covers exactly 2 heads of one of q/k/v.
// Q stored (b,h,T,36): [32 spatial][time][pad]. K,V stored (b,h,A,T),
// row 0 = time, rows 1..32 = spatial.
__global__ __launch_bounds__(256) void gemm_qkv_fl_kernel(
    const float* __restrict__ x,
    const float* __restrict__ Wq, const float* __restrict__ bq,
    const float* __restrict__ Wk, const float* __restrict__ bk,
    const float* __restrict__ Wv, const float* __restrict__ bv,
    float* __restrict__ Q, float* __restrict__ K, float* __restrict__ V)
{
    __shared__ float AsT[16][68];     // k-major
    __shared__ float BsT[16][68];
    __shared__ float sT[64][65];      // epilogue z-tile

    const int n0 = blockIdx.x * 64;   // 0..704
    const int m0 = blockIdx.y * 64;
    const int t  = threadIdx.x;
    const int tx = t & 15, ty = t >> 4;
    const int lr = t >> 2;            // 0..63
    const int lc = (t & 3) * 4;       // 0,4,8,12

    float acc[4][4];
    #pragma unroll
    for (int r = 0; r < 4; ++r)
        #pragma unroll
        for (int c = 0; c < 4; ++c) acc[r][c] = 0.f;

    const int og = n0 + lr;
    const float* Wsel = (og < 256) ? Wq : (og < 512 ? Wk : Wv);
    const int orow = og & 255;

    for (int k0 = 0; k0 < 512; k0 += 16) {
        const float4 av = *reinterpret_cast<const float4*>(&x[(m0 + lr) * 512 + k0 + lc]);
        AsT[lc + 0][lr] = av.x; AsT[lc + 1][lr] = av.y;
        AsT[lc + 2][lr] = av.z; AsT[lc + 3][lr] = av.w;
        const float4 bw = *reinterpret_cast<const float4*>(&Wsel[orow * 512 + k0 + lc]);
        BsT[lc + 0][lr] = bw.x; BsT[lc + 1][lr] = bw.y;
        BsT[lc + 2][lr] = bw.z; BsT[lc + 3][lr] = bw.w;
        __syncthreads();
        #pragma unroll
        for (int kk = 0; kk < 16; ++kk) {
            const float4 a4 = *reinterpret_cast<const float4*>(&AsT[kk][ty * 4]);
            const float4 b4 = *reinterpret_cast<const float4*>(&BsT[kk][tx * 4]);
            const float ar[4] = {a4.x, a4.y, a4.z, a4.w};
            const float br[4] = {b4.x, b4.y, b4.z, b4.w};
            #pragma unroll
            for (int r = 0; r < 4; ++r)
                #pragma unroll
                for (int c = 0; c < 4; ++c) acc[r][c] = fmaf(ar[r], br[c], acc[r][c]);
        }
        __syncthreads();
    }

    // epilogue: bias + stage tile in LDS
    #pragma unroll
    for (int c = 0; c < 4; ++c) {
        const int o = n0 + tx * 4 + c;
        const float* bsel = (o < 256) ? bq : (o < 512 ? bk : bv);
        const float bias = bsel[o & 255];
        #pragma unroll
        for (int r = 0; r < 4; ++r)
            sT[ty * 4 + r][tx * 4 + c] = acc[r][c] + bias;
    }
    __syncthreads();

    // FL lift: 128 threads, one (row, head) each
    if (t < 128) {
        const int m = t >> 1, half = t & 1;
        const int row = m0 + m;              // 0..1023
        const int b = row >> 9, tt = row & 511;
        const int which = n0 >> 8;           // 0=q 1=k 2=v
        const int h = ((n0 & 255) >> 5) + half;
        const int bh = b * Hq + h;

        float zv[32];
        float s2 = 0.f;
        #pragma unroll
        for (int k = 0; k < 32; ++k) { zv[k] = sT[m][half * 32 + k]; s2 = fmaf(zv[k], zv[k], s2); }
        const float rr = __builtin_amdgcn_sqrtf(s2);
        const float rs = fminf(fmaxf(rr, 1e-12f), 18.0f);
        const float e  = __expf(rs);
        const float ei = __builtin_amdgcn_rcpf(e);
        const float ch = 0.5f * (e + ei);
        float sc = 0.5f * (e - ei) / rs;
        if (rs < 1e-3f) sc = fmaf(rs * rs, 1.0f / 6.0f, 1.0f);
        float y0 = ch;
        float ys[32];
        float mink = -y0 * y0;
        #pragma unroll
        for (int k = 0; k < 32; ++k) { ys[k] = sc * zv[k]; mink = fmaf(ys[k], ys[k], mink); }
        const float inv = __builtin_amdgcn_rsqf(fmaxf(fabsf(mink), 1e-15f));
        y0 = fabsf(y0 * inv);

        if (which == 0) {
            float* qp = Q + (bh * Tq + tt) * QS;
            #pragma unroll
            for (int k = 0; k < 32; ++k) qp[k] = ys[k] * inv;
            qp[32] = y0;
        } else {
            float* p = ((which == 1) ? K : V) + bh * 33 * Tq + tt;
            p[0] = y0;
            #pragma unroll
            for (int k = 0; k < 32; ++k) p[(k + 1) * Tq] = ys[k] * inv;
        }
    }
}

// ---------------- Kernel 2: attention + Karcher step + origin log ----------
// 512 threads, 16 rows/block. Thread j owns column j in P1/P3; P4 regroups
// as 16 (row-block x a-chunk) groups x 32 j-lanes. Q read via scalar loads.
__global__ __launch_bounds__(512) void attn_kernel(
    const float* __restrict__ Q, const float* __restrict__ K,
    const float* __restrict__ V, float* __restrict__ Ztan)
{
    __shared__ float sBig[16 * 512];  // scores -> w  (P4 partials alias this)
    __shared__ float sM[16], sInv[16];
    __shared__ float sSp[16][8];
    __shared__ float sW[16][33];
    __shared__ float sSum[16];

    float (*sS)[512] = reinterpret_cast<float(*)[512]>(sBig);
    float (*part)[8][36] = reinterpret_cast<float(*)[8][36]>(sBig);

    const int bh = blockIdx.y;
    const int i0 = blockIdx.x * 16;
    const int t  = threadIdx.x;       // 0..511
    const int lane = t & 63, wv = t >> 6;

    const float* Qb = Q + (bh * Tq + i0) * QS;   // uniform
    const float* Kb = K + bh * 33 * Tq;
    const float* Vb = V + bh * 33 * Tq;

    // ---- P1: scores = -acosh(ip)^2, thread = column j -----------------
    {
        const int j = t;
        const float k0v = Kb[j];
        float ks[32];
        #pragma unroll
        for (int k = 0; k < 32; ++k) ks[k] = Kb[(k + 1) * Tq + j];
        #pragma unroll 4
        for (int i = 0; i < 16; ++i) {
            const float* qrow = Qb + i * QS;     // uniform -> s_load
            float d0 = 0.f, d1 = 0.f, d2 = 0.f, d3 = 0.f;
            #pragma unroll
            for (int c = 0; c < 8; ++c) {
                const float4 q4 = *reinterpret_cast<const float4*>(qrow + c * 4);
                d0 = fmaf(q4.x, ks[c * 4 + 0], d0);
                d1 = fmaf(q4.y, ks[c * 4 + 1], d1);
                d2 = fmaf(q4.z, ks[c * 4 + 2], d2);
                d3 = fmaf(q4.w, ks[c * 4 + 3], d3);
            }
            const float ip = qrow[32] * k0v - ((d0 + d1) + (d2 + d3));
            const float d  = facosh(fmaxf(ip, 1.0f + EPSF));
            sS[i][j] = -d * d;
        }
    }
    __syncthreads();

    // ---- P2: softmax stats, wave wv handles rows 2wv, 2wv+1 -----------
    #pragma unroll
    for (int ii = 0; ii < 2; ++ii) {
        const int i = wv * 2 + ii;
        float m = -1e30f;
        #pragma unroll
        for (int q = 0; q < 8; ++q) m = fmaxf(m, sS[i][lane + 64 * q]);
        #pragma unroll
        for (int off = 32; off > 0; off >>= 1) m = fmaxf(m, __shfl_xor(m, off, 64));
        float sum = 0.f;
        #pragma unroll
        for (int q = 0; q < 8; ++q) sum += __expf(sS[i][lane + 64 * q] - m);
        #pragma unroll
        for (int off = 32; off > 0; off >>= 1) sum += __shfl_xor(sum, off, 64);
        if (lane == 0) { sM[i] = m; sInv[i] = __builtin_amdgcn_rcpf(sum); }
    }
    __syncthreads();

    // ---- P3: w_ij = attn*dist(alpha); S partials; overwrite sS with w -
    {
        const int j = t;
        const float v0 = Vb[j];
        float vs[32];
        #pragma unroll
        for (int k = 0; k < 32; ++k) vs[k] = Vb[(k + 1) * Tq + j];
        float sp[16];
        #pragma unroll 4
        for (int i = 0; i < 16; ++i) {
            const float* qrow = Qb + i * QS;
            float d0 = 0.f, d1 = 0.f, d2 = 0.f, d3 = 0.f;
            #pragma unroll
            for (int c = 0; c < 8; ++c) {
                const float4 q4 = *reinterpret_cast<const float4*>(qrow + c * 4);
                d0 = fmaf(q4.x, vs[c * 4 + 0], d0);
                d1 = fmaf(q4.y, vs[c * 4 + 1], d1);
                d2 = fmaf(q4.z, vs[c * 4 + 2], d2);
                d3 = fmaf(q4.w, vs[c * 4 + 3], d3);
            }
            const float al = fmaxf(qrow[32] * v0 - ((d0 + d1) + (d2 + d3)), 1.0f + EPSF);
            const float dd = facosh(al);
            const float aij = __expf(sS[i][j] - sM[i]) * sInv[i];
            const float w = aij * dd;
            sS[i][j] = w;
            sp[i] = w * al;
        }
        #pragma unroll
        for (int i = 0; i < 16; ++i) {
            float v = sp[i];
            #pragma unroll
            for (int off = 32; off > 0; off >>= 1) v += __shfl_xor(v, off, 64);
            if (lane == 0) sSp[i][wv] = v;
        }
    }
    __syncthreads();

    // ---- P4: W[i][a] = sum_j w_ij * V[a][j] ---------------------------
    // 16 groups: g = ig*4 + ag; rows ig*4..ig*4+3, a-chunk ag*9..ag*9+8.
    {
        const int jl = t & 31, g = t >> 5;
        const int ig = g >> 2, ag = g & 3;
        const int abase = ag * 9;
        float acc[4][9];
        #pragma unroll
        for (int r = 0; r < 4; ++r)
            #pragma unroll
            for (int k = 0; k < 9; ++k) acc[r][k] = 0.f;

        #pragma unroll
        for (int q = 0; q < 16; ++q) {
            const int j = q * 32 + jl;
            const float w0 = sS[ig * 4 + 0][j];
            const float w1 = sS[ig * 4 + 1][j];
            const float w2 = sS[ig * 4 + 2][j];
            const float w3 = sS[ig * 4 + 3][j];
            #pragma unroll
            for (int k = 0; k < 9; ++k) {
                // ag==3 reads V rows 33..35: workspace pad rows (never used)
                const float v = Vb[(abase + k) * Tq + j];
                acc[0][k] = fmaf(w0, v, acc[0][k]);
                acc[1][k] = fmaf(w1, v, acc[1][k]);
                acc[2][k] = fmaf(w2, v, acc[2][k]);
                acc[3][k] = fmaf(w3, v, acc[3][k]);
            }
        }
        #pragma unroll
        for (int r = 0; r < 4; ++r)
            #pragma unroll
            for (int k = 0; k < 9; ++k) {
                float v = acc[r][k];
                v += __shfl_xor(v, 1, 64);
                v += __shfl_xor(v, 2, 64);
                acc[r][k] = v;
            }
        __syncthreads();   // all sS (w) reads complete before part overwrites
        if ((jl & 3) == 0) {
            const int sub = jl >> 2;
            #pragma unroll
            for (int r = 0; r < 4; ++r)
                #pragma unroll
                for (int k = 0; k < 9; ++k)
                    part[g][sub][r * 9 + k] = acc[r][k];
        }
    }
    __syncthreads();

    // ---- stage 2: fold 8 partials per (i,a); reduce S -----------------
    for (int task = t; task < 16 * 33; task += 512) {
        const int i = task / 33, a = task - i * 33;
        const int ag2 = a / 9, k = a - ag2 * 9;
        const int g2 = (i >> 2) * 4 + ag2;
        const int idx = (i & 3) * 9 + k;
        float s = 0.f;
        #pragma unroll
        for (int sub = 0; sub < 8; ++sub) s += part[g2][sub][idx];
        sW[i][a] = s;
    }
    if (t < 16) {
        float s = 0.f;
        #pragma unroll
        for (int w = 0; w < 8; ++w) s += sSp[t][w];
        sSum[t] = s;
    }
    __syncthreads();

    // ---- P5: degenerate exp_map + project + origin log-map ------------
    if (t < 16) {
        const int i = t;
        const float* qrow = Qb + i * QS;
        const float S  = sSum[i];
        const float q0 = qrow[32];
        const float y0 = fmaf(CINV, fmaf(S, q0, sW[i][0]), q0);
        float mink = -y0 * y0;
        float yv[32];
        #pragma unroll
        for (int a = 1; a < 33; ++a) {
            const float qa = qrow[a - 1];
            const float ya = fmaf(CINV, fmaf(S, qa, sW[i][a]), qa);
            yv[a - 1] = ya;
            mink = fmaf(ya, ya, mink);
        }
        const float inv = __builtin_amdgcn_rsqf(fmaxf(fabsf(mink), 1e-15f));
        const float Y0 = fabsf(y0 * inv);
        const float dist0 = facosh(fmaxf(Y0, 1.0f + EPSF));
        const float coef = dist0 * CINV;
        const int b = bh >> 3, h = bh & 7;
        float* zp = Ztan + ((b * Tq + (i0 + i)) * 264) + h * 33;
        zp[0] = coef * (2.0f * Y0);
        #pragma unroll
        for (int a = 1; a < 33; ++a) zp[a] = coef * (yv[a - 1] * inv);
    }
}

// ---------------- Kernel 3: Z = Ztan(1024x264) @ Wo^T + bo -----------------
__global__ __launch_bounds__(256) void out_gemm_kernel(
    const float* __restrict__ Ztan, const float* __restrict__ Wo,
    const float* __restrict__ bo, float* __restrict__ out)
{
    __shared__ float AsT[8][68];
    __shared__ float BsT[8][68];
    const int n0 = blockIdx.x * 64;
    const int m0 = blockIdx.y * 64;
    const int t  = threadIdx.x;
    const int tx = t & 15, ty = t >> 4;
    const int lr = t >> 2;
    const int lc = (t & 3) * 2;

    float acc[4][4];
    #pragma unroll
    for (int r = 0; r < 4; ++r)
        #pragma unroll
        for (int c = 0; c < 4; ++c) acc[r][c] = 0.f;

    for (int k0 = 0; k0 < 264; k0 += 8) {
        const float2 av = *reinterpret_cast<const float2*>(&Ztan[(m0 + lr) * 264 + k0 + lc]);
        AsT[lc][lr] = av.x; AsT[lc + 1][lr] = av.y;
        const float2 bw = *reinterpret_cast<const float2*>(&Wo[(n0 + lr) * 264 + k0 + lc]);
        BsT[lc][lr] = bw.x; BsT[lc + 1][lr] = bw.y;
        __syncthreads();
        #pragma unroll
        for (int kk = 0; kk < 8; ++kk) {
            const float4 a4 = *reinterpret_cast<const float4*>(&AsT[kk][ty * 4]);
            const float4 b4 = *reinterpret_cast<const float4*>(&BsT[kk][tx * 4]);
            const float ar[4] = {a4.x, a4.y, a4.z, a4.w};
            const float br[4] = {b4.x, b4.y, b4.z, b4.w};
            #pragma unroll
            for (int r = 0; r < 4; ++r)
                #pragma unroll
                for (int c = 0; c < 4; ++c) acc[r][c] = fmaf(ar[r], br[c], acc[r][c]);
        }
        __syncthreads();
    }
    #pragma unroll
    for (int c = 0; c < 4; ++c) {
        const int o = n0 + tx * 4 + c;
        const float bias = bo[o];
        #pragma unroll
        for (int r = 0; r < 4; ++r)
            out[(m0 + ty * 4 + r) * 512 + o] = acc[r][c] + bias;
    }
}

} // namespace

// ---------------------------------------------------------------------------
extern "C" void kernel_launch(void* const* d_in, const int* in_sizes, int n_in,
                              void* d_out, int out_size, void* d_ws, size_t ws_size,
                              hipStream_t stream)
{
    const float* x  = (const float*)d_in[0];
    const float* Wq = (const float*)d_in[1];
    const float* bq = (const float*)d_in[2];
    const float* Wk = (const float*)d_in[3];
    const float* bk = (const float*)d_in[4];
    const float* Wv = (const float*)d_in[5];
    const float* bv = (const float*)d_in[6];
    const float* Wo = (const float*)d_in[7];
    const float* bo = (const float*)d_in[8];
    float* out = (float*)d_out;

    float* ws   = (float*)d_ws;
    float* Qw   = ws;                   // 16*512*36            = 294912
    float* Kw   = ws + 294912;          // 16*33*512 (+pad 3*512*... ) -> 272384
    float* Vw   = ws + 294912 + 272384; // 16*33*512 + 3-row over-read pad
    float* Zt   = ws + 294912 + 2 * 272384;  // 1024*264 = 270336

    gemm_qkv_fl_kernel<<<dim3(12, 16), 256, 0, stream>>>(x, Wq, bq, Wk, bk, Wv, bv,
                                                         Qw, Kw, Vw);
    attn_kernel<<<dim3(32, 16), 512, 0, stream>>>(Qw, Kw, Vw, Zt);
    out_gemm_kernel<<<dim3(8, 16), 256, 0, stream>>>(Zt, Wo, bo, out);
}